// Round 1
// baseline (317.777 us; speedup 1.0000x reference)
//
#include <hip/hip_runtime.h>

#define B_   32
#define C_   64
#define H_   128
#define W_   128
#define HW_  (H_ * W_)       // 16384
#define CHW_ (C_ * HW_)      // 1048576
#define TH_  8               // output rows per block

// Fused: box-mean(3x3, edge-clipped) -> 1x1 conv (64x64) -> residual add.
// One block per (batch, 8-row strip). 256 threads.
__global__ __launch_bounds__(256, 2) void denoise_fused(
    const float* __restrict__ x, const float* __restrict__ cw,
    const float* __restrict__ cb, float* __restrict__ out)
{
    __shared__ float tile[C_ * W_];   // 8192 floats (32 KB): vert-sums, then xd
    __shared__ float Wt[C_ * C_];     // Wt[c*64+o] = cw[o*64+c] (16 KB)
    __shared__ float bias[C_];

    const int t  = threadIdx.x;
    const int b  = blockIdx.x >> 4;          // 32 batches
    const int h0 = (blockIdx.x & 15) * TH_;  // 16 strips of 8 rows

    // Stage transposed weights + bias (once per block).
    for (int i = t; i < C_ * C_; i += 256) {
        int o = i >> 6, c = i & 63;
        Wt[c * 64 + o] = cw[i];
    }
    if (t < C_) bias[t] = cb[t];
    __syncthreads();

    const float* xb = x   + (size_t)b * CHW_;
    float*       ob = out + (size_t)b * CHW_;

    const int wt = t & 31;   // w-tile index: 4 consecutive floats
    const int ot = t >> 5;   // o-tile index: 8 consecutive out-channels

    for (int r = 0; r < TH_; ++r) {
        const int h = h0 + r;
        const bool hm = (h > 0), hp = (h < H_ - 1);

        // ---- Phase A: vertical 3-row sums (edge-clipped) into LDS ----
        const float4* rowc = (const float4*)(xb + h * W_);
        const float4* rowm = (const float4*)(xb + (h - 1) * W_);
        const float4* rowp = (const float4*)(xb + (h + 1) * W_);
        #pragma unroll
        for (int k = 0; k < 8; ++k) {
            int vi  = t + k * 256;        // float4 slot in [C,W] row-plane
            int c   = vi >> 5;            // 32 float4 per 128-wide row
            int f4  = vi & 31;
            int off = c * (HW_ / 4) + f4; // float4 offset from row base
            float4 s = rowc[off];
            if (hm) { float4 a = rowm[off]; s.x += a.x; s.y += a.y; s.z += a.z; s.w += a.w; }
            if (hp) { float4 a = rowp[off]; s.x += a.x; s.y += a.y; s.z += a.z; s.w += a.w; }
            ((float4*)tile)[vi] = s;
        }
        __syncthreads();

        // ---- Phase B: horizontal sum + divide-by-count (in regs) ----
        float4 xd[8];
        const float rv = 1.f + (hm ? 1.f : 0.f) + (hp ? 1.f : 0.f);
        const float i3 = 1.f / (rv * 3.f);
        const float i2 = 1.f / (rv * 2.f);
        #pragma unroll
        for (int k = 0; k < 8; ++k) {
            int vi = t + k * 256;
            int c  = vi >> 5;
            int w4 = (vi & 31) << 2;
            float4 v = ((const float4*)tile)[vi];
            float L = (w4 == 0)        ? 0.f : tile[c * W_ + w4 - 1];
            float R = (w4 == W_ - 4)   ? 0.f : tile[c * W_ + w4 + 4];
            float4 d;
            d.x = (L   + v.x + v.y) * ((w4 == 0)      ? i2 : i3);
            d.y = (v.x + v.y + v.z) * i3;
            d.z = (v.y + v.z + v.w) * i3;
            d.w = (v.z + v.w + R)   * ((w4 == W_ - 4) ? i2 : i3);
            xd[k] = d;
        }
        __syncthreads();
        #pragma unroll
        for (int k = 0; k < 8; ++k) ((float4*)tile)[t + k * 256] = xd[k];
        __syncthreads();

        // ---- Phase C: 64x64 matmul over channels, 8(o) x 4(w) per thread ----
        float acc[8][4];
        #pragma unroll
        for (int oi = 0; oi < 8; ++oi) {
            float bv = bias[ot * 8 + oi];
            acc[oi][0] = bv; acc[oi][1] = bv; acc[oi][2] = bv; acc[oi][3] = bv;
        }
        #pragma unroll 4
        for (int c = 0; c < C_; ++c) {
            float4 xv = ((const float4*)tile)[c * 32 + wt];
            float4 wa = ((const float4*)Wt)[c * 16 + ot * 2];
            float4 wb = ((const float4*)Wt)[c * 16 + ot * 2 + 1];
            float w8[8] = { wa.x, wa.y, wa.z, wa.w, wb.x, wb.y, wb.z, wb.w };
            #pragma unroll
            for (int oi = 0; oi < 8; ++oi) {
                acc[oi][0] += w8[oi] * xv.x;
                acc[oi][1] += w8[oi] * xv.y;
                acc[oi][2] += w8[oi] * xv.z;
                acc[oi][3] += w8[oi] * xv.w;
            }
        }

        // ---- Epilogue: residual add + store (coalesced float4) ----
        #pragma unroll
        for (int oi = 0; oi < 8; ++oi) {
            int o = ot * 8 + oi;
            const float4* xr = (const float4*)(xb + o * HW_ + h * W_);
            float4 v = xr[wt];
            float4 res;
            res.x = v.x + acc[oi][0];
            res.y = v.y + acc[oi][1];
            res.z = v.z + acc[oi][2];
            res.w = v.w + acc[oi][3];
            ((float4*)(ob + o * HW_ + h * W_))[wt] = res;
        }
        __syncthreads();  // protect tile before next row's Phase A
    }
}

extern "C" void kernel_launch(void* const* d_in, const int* in_sizes, int n_in,
                              void* d_out, int out_size, void* d_ws, size_t ws_size,
                              hipStream_t stream) {
    const float* x  = (const float*)d_in[0];
    const float* cw = (const float*)d_in[1];
    const float* cb = (const float*)d_in[2];
    float* out = (float*)d_out;
    dim3 grid(B_ * (H_ / TH_));   // 512 blocks
    dim3 block(256);
    hipLaunchKernelGGL(denoise_fused, grid, block, 0, stream, x, cw, cb, out);
}

// Round 3
// 313.345 us; speedup vs baseline: 1.0141x; 1.0141x over previous
//
#include <hip/hip_runtime.h>

#define B_   32
#define C_   64
#define H_   128
#define W_   128
#define HW_  (H_ * W_)       // 16384
#define CHW_ (C_ * HW_)      // 1048576
#define TH_  4               // output rows per block

// Fused: box-mean(3x3, edge-clipped) -> 1x1 conv (64x64) -> residual add.
// Block = (batch, 4-row strip), 256 threads = 4 waves.
// Filter phase: wave owns 2 channels/pass, vertical sum from 3 global rows in
// registers, horizontal sum via shfl (edge lanes don't use the crossing), one
// LDS write. Matmul phase: wave owns 16 out-channels, lane = (o-oct, w-f4),
// 8x4 accum tile. 2 barriers/row.
__global__ __launch_bounds__(256, 3) void denoise_fused(
    const float* __restrict__ x, const float* __restrict__ cw,
    const float* __restrict__ cb, float* __restrict__ out)
{
    __shared__ float xd[C_ * W_];   // 32 KB: denoised activations for one row
    __shared__ float Wt[C_ * C_];   // 16 KB: Wt[c*64+o] = cw[o*64+c]

    const int t    = threadIdx.x;
    const int b    = blockIdx.x >> 5;          // 32 batches
    const int h0   = (blockIdx.x & 31) * TH_;  // 32 strips of 4 rows
    const int lane = t & 63;
    const int wid  = t >> 6;                   // wave 0..3
    const int j    = lane & 31;                // f4 index along W (w = 4j..4j+3)
    const int half = lane >> 5;                // 0/1

    // --- Stage Wt transposed, conflict-free, via xd as scratch ---
    for (int i = t; i < C_ * C_; i += 256) {
        int o = i >> 6, c = i & 63;
        xd[o * 65 + c] = cw[i];                // coalesced read, padded write
    }
    __syncthreads();
    for (int i = t; i < C_ * C_; i += 256) {
        int c = i >> 6, o = i & 63;
        Wt[i] = xd[o * 65 + c];                // (o+c)%32 banks: conflict-free
    }
    __syncthreads();

    const float* xb = x   + (size_t)b * CHW_;
    float*       ob = out + (size_t)b * CHW_;

    const int o0 = wid * 16 + half * 8;        // this lane's 8 out-channels
    float bias[8];
    #pragma unroll
    for (int oi = 0; oi < 8; ++oi) bias[oi] = cb[o0 + oi];

    for (int r = 0; r < TH_; ++r) {
        const int h = h0 + r;
        const bool hm = (h > 0), hp = (h < H_ - 1);
        const float rv = 1.f + (hm ? 1.f : 0.f) + (hp ? 1.f : 0.f);
        const float i3 = 1.f / (rv * 3.f);
        const float i2 = 1.f / (rv * 2.f);

        // ---- Filter: 8 passes x (4 waves x 2 channels) = 64 channels ----
        #pragma unroll
        for (int p = 0; p < 8; ++p) {
            const int c = p * 8 + wid * 2 + half;
            const float* rc = xb + c * HW_ + h * W_;
            float4 v = ((const float4*)rc)[j];
            if (hm) { float4 a = ((const float4*)(rc - W_))[j]; v.x += a.x; v.y += a.y; v.z += a.z; v.w += a.w; }
            if (hp) { float4 a = ((const float4*)(rc + W_))[j]; v.x += a.x; v.y += a.y; v.z += a.z; v.w += a.w; }
            // horizontal neighbors from adjacent lanes (garbage at the
            // 31<->32 crossing is masked: those lanes are image edges)
            float L = __shfl_up(v.w, 1);
            float R = __shfl_down(v.x, 1);
            float4 d;
            d.x = (j == 0)  ? (v.x + v.y) * i2 : (L + v.x + v.y) * i3;
            d.y = (v.x + v.y + v.z) * i3;
            d.z = (v.y + v.z + v.w) * i3;
            d.w = (j == 31) ? (v.z + v.w) * i2 : (v.z + v.w + R) * i3;
            ((float4*)xd)[c * 32 + j] = d;
        }
        __syncthreads();

        // ---- 64x64 matmul over channels: 8(o) x 4(w) per lane ----
        float acc[8][4];
        #pragma unroll
        for (int oi = 0; oi < 8; ++oi)
            acc[oi][0] = acc[oi][1] = acc[oi][2] = acc[oi][3] = 0.f;

        #pragma unroll 4
        for (int c = 0; c < C_; ++c) {
            float4 xv = ((const float4*)xd)[c * 32 + j];
            float4 wa = *(const float4*)&Wt[c * 64 + o0];      // 2-addr bcast
            float4 wb = *(const float4*)&Wt[c * 64 + o0 + 4];
            float w8[8] = { wa.x, wa.y, wa.z, wa.w, wb.x, wb.y, wb.z, wb.w };
            #pragma unroll
            for (int oi = 0; oi < 8; ++oi) {
                acc[oi][0] += w8[oi] * xv.x;
                acc[oi][1] += w8[oi] * xv.y;
                acc[oi][2] += w8[oi] * xv.z;
                acc[oi][3] += w8[oi] * xv.w;
            }
        }

        // ---- Epilogue: bias + residual + coalesced store ----
        #pragma unroll
        for (int oi = 0; oi < 8; ++oi) {
            const int o = o0 + oi;
            float4 xr = ((const float4*)(xb + o * HW_ + h * W_))[j];
            float4 res;
            res.x = xr.x + acc[oi][0] + bias[oi];
            res.y = xr.y + acc[oi][1] + bias[oi];
            res.z = xr.z + acc[oi][2] + bias[oi];
            res.w = xr.w + acc[oi][3] + bias[oi];
            ((float4*)(ob + o * HW_ + h * W_))[j] = res;
        }
        __syncthreads();   // protect xd before next row's writes
    }
}

extern "C" void kernel_launch(void* const* d_in, const int* in_sizes, int n_in,
                              void* d_out, int out_size, void* d_ws, size_t ws_size,
                              hipStream_t stream) {
    const float* x  = (const float*)d_in[0];
    const float* cw = (const float*)d_in[1];
    const float* cb = (const float*)d_in[2];
    float* out = (float*)d_out;
    dim3 grid(B_ * (H_ / TH_));   // 1024 blocks
    dim3 block(256);
    hipLaunchKernelGGL(denoise_fused, grid, block, 0, stream, x, cw, cb, out);
}